// Round 2
// baseline (409.120 us; speedup 1.0000x reference)
//
#include <hip/hip_runtime.h>
#include <math.h>

// Problem constants (B, N, D) = (256, 128, 128)
#define B_    256
#define N_    128
#define MAXP  30
#define OTHER_ 35      // D - 2*30 - 1 - 32
#define CIN1  131      // D + 64 - 2*30 - 1
#define NIDX  381      // 3*(N-1)

// ---------------------------------------------------------------------------
// Fused prep: idx convert (with per-wave int64 detection) + 3 weight
// transposes. w (O, Kreal) row-major -> wT (Kpad, O), zero-pad rows.
// ---------------------------------------------------------------------------
__global__ __launch_bounds__(256) void prep_kernel(
    const void* __restrict__ rawIdx, int* __restrict__ idx32,
    const float* __restrict__ w1, float* __restrict__ wT1,
    const float* __restrict__ w2, float* __restrict__ wT2,
    const float* __restrict__ w3, float* __restrict__ wT3) {
  constexpr int S0 = B_ * NIDX;        // 97536 (381 full blocks)
  constexpr int S1 = 396 * 256;        // wT1
  constexpr int S2 = 768 * 128;        // wT2
  constexpr int S3 = 384 * 64;         // wT3
  const int gid = blockIdx.x * 256 + threadIdx.x;
  if (gid < S0) {
    // wave-uniform int64-vs-int32 detection (int64 LE view: (v,0,v,0,...))
    const int* r32 = (const int*)rawIdx;
    const int lane = threadIdx.x & 63;
    const int lo = r32[2 * lane];
    const int hi = r32[2 * lane + 1];
    const bool ok = (hi == 0 && lo >= 0 && lo < N_);
    const bool is64 = __all(ok);
    idx32[gid] = is64 ? (int)((const long long*)rawIdx)[gid] : r32[gid];
  } else if (gid < S0 + S1) {
    const int l = gid - S0;
    const int k = l >> 8, o = l & 255;          // Kpad=396, O=256
    wT1[l] = (k < 393) ? w1[o * 393 + k] : 0.f;
  } else if (gid < S0 + S1 + S2) {
    const int l = gid - (S0 + S1);
    const int k = l >> 7, o = l & 127;          // Kpad=768, O=128
    wT2[l] = w2[o * 768 + k];
  } else if (gid < S0 + S1 + S2 + S3) {
    const int l = gid - (S0 + S1 + S2);
    const int k = l >> 6, o = l & 63;           // Kpad=384, O=64
    wT3[l] = w3[o * 384 + k];
  }
}

// ---------------------------------------------------------------------------
// Embedding + collate: one wave per node, ids loaded lane-parallel once.
// feature (B, 128, 128) [b][d][n]; collate (B, 128, 131) node-major.
// ---------------------------------------------------------------------------
__global__ __launch_bounds__(256) void embed_kernel(
    const float* __restrict__ feature,
    const float* __restrict__ col_embed,   // (200,32)
    const float* __restrict__ op_embed,    // (20,32)
    float* __restrict__ collate) {
  const int tid  = threadIdx.x;
  const int wave = tid >> 6;
  const int lane = tid & 63;
  const int b = blockIdx.x >> 5;
  const int n = ((blockIdx.x & 31) << 2) | wave;

  const float* fb = feature + ((size_t)b * 128) * 128 + n;  // stride 128 over d

  int civ = 0, oiv = 0;
  if (lane < MAXP) civ = (int)fb[(OTHER_ + lane) * 128];
  if (lane >= 32 && lane < 32 + MAXP) oiv = (int)fb[(OTHER_ + MAXP + (lane - 32)) * 128];
  const int L = (int)fb[95 * 128];  // length in [0,30], wave-uniform

  const float* tp = (lane < 32) ? col_embed : op_embed;
  const int cl = lane & 31;
  float acc = 0.f;
  for (int i = 0; i < L; ++i) {
    const int cv = __shfl(civ, i);
    const int ov = __shfl(oiv, 32 + i);
    const int row = (lane < 32) ? cv : ov;
    acc += tp[row * 32 + cl];
  }

  float* out = collate + ((size_t)b * 128 + n) * CIN1;
  out[35 + lane] = acc;                                     // emb-sum (64)
  if (lane < 35) out[lane] = fb[lane * 128];                // others
  if (lane < 32) out[99 + lane] = fb[(96 + lane) * 128];    // param
}

// ---------------------------------------------------------------------------
// Tree conv layer v2: block = (batch, chunk). 512 threads. 2 blocks/CU (LDS
// <= ~71 KB). Each block produces 64 output channels x NJ nodes.
//   SPLITJ=false: chunk = oc-chunk (oc0 = chunk*64), all 128 nodes
//   SPLITJ=true : chunk = j-half  (jbase = chunk*64), all 64 oc
// Channels staged in NSTAGE sequential LDS stages of CST (regs accumulate).
// Norm of the INPUT is applied at staging time from partial stats (NCH_IN
// double2 partials combined in fixed order -> deterministic).
// Output stats written as per-chunk partial double2 {sum, sumsq}.
// ---------------------------------------------------------------------------
template <int CINREAL, int CST, int CINP, int COUTtot, int JPT,
          bool NORM_IN, int NCH_IN, int NSTAGE, int NCHOUT, bool SPLITJ>
__global__ __launch_bounds__(512, 1) void conv_kernel(
    const float* __restrict__ X,        // (B,128,CINREAL) node-major
    const int* __restrict__ idx,        // (B,381)
    const float* __restrict__ wT,       // (3*CST*NSTAGE(+pad), COUTtot)
    const float* __restrict__ bias,     // (COUTtot)
    const double* __restrict__ statsIn, // (B, NCH_IN, 2) partials
    float* __restrict__ Y,              // (B,128,COUTtot) node-major
    double* __restrict__ statsOut) {    // (B, NCHOUT, 2) partials
  __shared__ float xs[128 * CINP];
  __shared__ int nb_s[NIDX];
  __shared__ double red[16];

  const int b = blockIdx.x;
  const int chunk = blockIdx.y;
  const int oc0 = SPLITJ ? 0 : chunk * 64;
  const int jbase = SPLITJ ? chunk * 64 : 0;
  const int tid = threadIdx.x;

  float mean = 0.f, inv = 1.f;
  if (NORM_IN) {
    double S = 0.0, Q = 0.0;
#pragma unroll
    for (int i = 0; i < NCH_IN; ++i) {
      S += statsIn[(b * NCH_IN + i) * 2];
      Q += statsIn[(b * NCH_IN + i) * 2 + 1];
    }
    const double cnt = (double)CINREAL * 128.0;
    const double m = S / cnt;
    double var = (Q - S * S / cnt) / (cnt - 1.0);
    if (var < 0.0) var = 0.0;
    mean = (float)m;
    inv = (float)(1.0 / (sqrt(var) + 1e-5));
  }

  if (tid < NIDX) nb_s[tid] = idx[b * NIDX + tid];

  const int tx = tid & 15;   // 4 consecutive oc each -> 64 oc
  const int ty = tid >> 4;   // 32 groups of JPT consecutive j

  float acc[4][JPT];
#pragma unroll
  for (int i = 0; i < 4; ++i)
#pragma unroll
    for (int jj = 0; jj < JPT; ++jj) acc[i][jj] = 0.f;

  const float* __restrict__ Xb = X + (size_t)b * (128 * CINREAL);

  int rowoff[JPT][3];
  double s_sum = 0.0, s_sq = 0.0;

  for (int s = 0; s < NSTAGE; ++s) {
    if (s > 0) __syncthreads();  // protect prior stage reads before overwrite
    // ---- stage CST channels (global c in [s*CST, s*CST+CST)) ----
    for (int t = tid; t < 128 * CST; t += 512) {
      const int n = t / CST;
      const int c = t - n * CST;
      const int gc = s * CST + c;
      float v = 0.f;
      if (gc < CINREAL) {
        v = Xb[n * CINREAL + gc];
        if (NORM_IN) {
          v = (v - mean) * inv;
          v = (v > 0.f) ? v : 0.01f * v;
        }
      }
      xs[n * CINP + c] = v;
    }
    __syncthreads();

    if (s == 0) {
#pragma unroll
      for (int jj = 0; jj < JPT; ++jj) {
        const int j = jbase + ty * JPT + jj;
#pragma unroll
        for (int kk = 0; kk < 3; ++kk) {
          const int nbv = (j > 0) ? nb_s[(j - 1) * 3 + kk] : 0;
          rowoff[jj][kk] = nbv * CINP;
        }
      }
    }

    const float* wp = wT + ((size_t)s * CST * 3) * COUTtot + oc0 + tx * 4;

    for (int c = 0; c < CST; c += 4) {
      float xq[JPT][3][4];
#pragma unroll
      for (int jj = 0; jj < JPT; ++jj)
#pragma unroll
        for (int kk = 0; kk < 3; ++kk)
          *reinterpret_cast<float4*>(xq[jj][kk]) =
              *reinterpret_cast<const float4*>(&xs[rowoff[jj][kk] + c]);

#pragma unroll
      for (int cc = 0; cc < 4; ++cc) {
#pragma unroll
        for (int kk = 0; kk < 3; ++kk) {
          const float4 w4 = *reinterpret_cast<const float4*>(wp);
          wp += COUTtot;
#pragma unroll
          for (int jj = 0; jj < JPT; ++jj) {
            const float xv = xq[jj][kk][cc];
            acc[0][jj] = fmaf(w4.x, xv, acc[0][jj]);
            acc[1][jj] = fmaf(w4.y, xv, acc[1][jj]);
            acc[2][jj] = fmaf(w4.z, xv, acc[2][jj]);
            acc[3][jj] = fmaf(w4.w, xv, acc[3][jj]);
          }
        }
      }
    }
  }

  // ---- epilogue: bias, zero column, stats partial, store ----
  const float4 b4 = *reinterpret_cast<const float4*>(bias + oc0 + tx * 4);
#pragma unroll
  for (int jj = 0; jj < JPT; ++jj) {
    const int j = jbase + ty * JPT + jj;
    float4 o4;
    if (j > 0) {
      o4.x = acc[0][jj] + b4.x;
      o4.y = acc[1][jj] + b4.y;
      o4.z = acc[2][jj] + b4.z;
      o4.w = acc[3][jj] + b4.w;
    } else {
      o4.x = 0.f; o4.y = 0.f; o4.z = 0.f; o4.w = 0.f;
    }
    s_sum += (double)o4.x + (double)o4.y + (double)o4.z + (double)o4.w;
    s_sq  += (double)o4.x * o4.x + (double)o4.y * o4.y +
             (double)o4.z * o4.z + (double)o4.w * o4.w;
    *reinterpret_cast<float4*>(Y + ((size_t)b * 128 + j) * COUTtot + oc0 + tx * 4) = o4;
  }

#pragma unroll
  for (int o = 32; o > 0; o >>= 1) {
    s_sum += __shfl_down(s_sum, o, 64);
    s_sq  += __shfl_down(s_sq, o, 64);
  }
  const int w = tid >> 6;
  if ((tid & 63) == 0) { red[w * 2] = s_sum; red[w * 2 + 1] = s_sq; }
  __syncthreads();
  if (tid == 0) {
    double S = 0.0, Q = 0.0;
#pragma unroll
    for (int i = 0; i < 8; ++i) { S += red[i * 2]; Q += red[i * 2 + 1]; }
    statsOut[(b * NCHOUT + chunk) * 2] = S;
    statsOut[(b * NCHOUT + chunk) * 2 + 1] = Q;
  }
}

// ---------------------------------------------------------------------------
// Final: combine conv3 stats partials, normalize, maxpool, 2-layer MLP.
// ---------------------------------------------------------------------------
__global__ __launch_bounds__(64) void final_kernel(
    const float* __restrict__ Y3,      // (B,128,64)
    const double* __restrict__ st,     // (B,2,2) partials
    const float* __restrict__ fw1,     // (32,64)
    const float* __restrict__ fb1,     // (32)
    const float* __restrict__ fw2,     // (1,32)
    const float* __restrict__ fb2,     // (1)
    float* __restrict__ out) {
  const int b = blockIdx.x;
  const int lane = threadIdx.x;

  const double S = st[(b * 2) * 2] + st[(b * 2 + 1) * 2];
  const double Q = st[(b * 2) * 2 + 1] + st[(b * 2 + 1) * 2 + 1];
  const double cnt = 64.0 * 128.0;
  const double m = S / cnt;
  double var = (Q - S * S / cnt) / (cnt - 1.0);
  if (var < 0.0) var = 0.0;
  const float mean = (float)m;
  const float inv = (float)(1.0 / (sqrt(var) + 1e-5));

  const float* Yb = Y3 + (size_t)b * 128 * 64;
  float mx = -3.4e38f;
  for (int n = 0; n < 128; ++n) {
    const float v = (Yb[n * 64 + lane] - mean) * inv;
    mx = fmaxf(mx, v);
  }
  __shared__ float pooled[64];
  __shared__ float hs[32];
  pooled[lane] = mx;
  __syncthreads();
  if (lane < 32) {
    float a = fb1[lane];
    for (int c = 0; c < 64; ++c) a = fmaf(pooled[c], fw1[lane * 64 + c], a);
    hs[lane] = fmaxf(a, 0.f);
  }
  __syncthreads();
  if (lane == 0) {
    float s = fb2[0];
    for (int t = 0; t < 32; ++t) s = fmaf(hs[t], fw2[t], s);
    out[b] = s;
  }
}

// ---------------------------------------------------------------------------
extern "C" void kernel_launch(void* const* d_in, const int* in_sizes, int n_in,
                              void* d_out, int out_size, void* d_ws, size_t ws_size,
                              hipStream_t stream) {
  const float* feature   = (const float*)d_in[0];
  const void*  indexes   = d_in[1];
  const float* col_embed = (const float*)d_in[2];
  const float* op_embed  = (const float*)d_in[3];
  const float* w1  = (const float*)d_in[4];
  const float* b1  = (const float*)d_in[5];
  const float* w2  = (const float*)d_in[6];
  const float* b2  = (const float*)d_in[7];
  const float* w3  = (const float*)d_in[8];
  const float* b3  = (const float*)d_in[9];
  const float* fw1 = (const float*)d_in[10];
  const float* fb1 = (const float*)d_in[11];
  const float* fw2 = (const float*)d_in[12];
  const float* fb2 = (const float*)d_in[13];
  float* out = (float*)d_out;

  char* ws = (char*)d_ws;
  size_t off = 0;
  auto carve = [&](size_t bytes) -> char* {
    off = (off + 255) & ~(size_t)255;
    char* p = ws + off;
    off += bytes;
    return p;
  };
  int*    idx32   = (int*)carve((size_t)B_ * NIDX * sizeof(int));
  float*  wT1     = (float*)carve((size_t)396 * 256 * sizeof(float));
  float*  wT2     = (float*)carve((size_t)768 * 128 * sizeof(float));
  float*  wT3     = (float*)carve((size_t)384 * 64 * sizeof(float));
  float*  collate = (float*)carve((size_t)B_ * 128 * CIN1 * sizeof(float));
  float*  Y1      = (float*)carve((size_t)B_ * 128 * 256 * sizeof(float));
  float*  Y2      = (float*)carve((size_t)B_ * 128 * 128 * sizeof(float));
  float*  Y3      = (float*)carve((size_t)B_ * 128 * 64 * sizeof(float));
  double* st1     = (double*)carve((size_t)B_ * 4 * 2 * sizeof(double));
  double* st2     = (double*)carve((size_t)B_ * 2 * 2 * sizeof(double));
  double* st3     = (double*)carve((size_t)B_ * 2 * 2 * sizeof(double));
  (void)ws_size; (void)in_sizes; (void)n_in; (void)out_size;

  constexpr int PREP_TOTAL = B_ * NIDX + 396 * 256 + 768 * 128 + 384 * 64;
  hipLaunchKernelGGL(prep_kernel, dim3((PREP_TOTAL + 255) / 256), dim3(256), 0, stream,
                     indexes, idx32, w1, wT1, w2, wT2, w3, wT3);
  hipLaunchKernelGGL(embed_kernel, dim3(B_ * 32), dim3(256), 0, stream,
                     feature, col_embed, op_embed, collate);
  // conv1: CIN 131, 1 stage of 132 (CINP 136), COUT 256 in 4 oc-chunks
  hipLaunchKernelGGL((conv_kernel<131, 132, 136, 256, 4, false, 1, 1, 4, false>),
                     dim3(B_, 4), dim3(512), 0, stream,
                     collate, idx32, wT1, b1, (const double*)nullptr, Y1, st1);
  // conv2: CIN 256, 2 stages of 128 (CINP 132), COUT 128 in 2 oc-chunks
  hipLaunchKernelGGL((conv_kernel<256, 128, 132, 128, 4, true, 4, 2, 2, false>),
                     dim3(B_, 2), dim3(512), 0, stream,
                     Y1, idx32, wT2, b2, st1, Y2, st2);
  // conv3: CIN 128, 1 stage (CINP 132), COUT 64, 2 j-halves
  hipLaunchKernelGGL((conv_kernel<128, 128, 132, 64, 2, true, 2, 1, 2, true>),
                     dim3(B_, 2), dim3(512), 0, stream,
                     Y2, idx32, wT3, b3, st2, Y3, st3);
  hipLaunchKernelGGL(final_kernel, dim3(B_), dim3(64), 0, stream,
                     Y3, st3, fw1, fb1, fw2, fb2, out);
}

// Round 3
// 333.725 us; speedup vs baseline: 1.2259x; 1.2259x over previous
//
#include <hip/hip_runtime.h>
#include <math.h>

// Problem constants (B, N, D) = (256, 128, 128)
#define B_    256
#define N_    128
#define MAXP  30
#define OTHER_ 35      // D - 2*30 - 1 - 32
#define CIN1  131      // D + 64 - 2*30 - 1
#define NIDX  381      // 3*(N-1)

// wT layouts (kk-major): row r = kk*CINTOT + c, columns = COUT
#define CINTOT1 136
#define CINTOT2 256
#define CINTOT3 128
#define S_IDX  (B_ * NIDX)          // 97536
#define S_W1   (3 * CINTOT1 * 256)  // 104448
#define S_W2   (3 * CINTOT2 * 128)  // 98304
#define S_W3   (3 * CINTOT3 * 64)   // 24576

// ---------------------------------------------------------------------------
// Fused prep: idx convert (wave-uniform int64 detection) + 3 weight
// transposes into kk-major layout wT[kk*CINTOT + c][o], zero-padded rows.
// ---------------------------------------------------------------------------
__global__ __launch_bounds__(256) void prep_kernel(
    const void* __restrict__ rawIdx, int* __restrict__ idx32,
    const float* __restrict__ w1, float* __restrict__ wT1,
    const float* __restrict__ w2, float* __restrict__ wT2,
    const float* __restrict__ w3, float* __restrict__ wT3) {
  const int gid = blockIdx.x * 256 + threadIdx.x;
  if (gid < S_IDX) {
    // int64 LE view is (v,0,v,0,...) with v in [0,128)
    const int* r32 = (const int*)rawIdx;
    const int lane = threadIdx.x & 63;
    const int lo = r32[2 * lane];
    const int hi = r32[2 * lane + 1];
    const bool ok = (hi == 0 && lo >= 0 && lo < N_);
    const bool is64 = __all(ok);
    idx32[gid] = is64 ? (int)((const long long*)rawIdx)[gid] : r32[gid];
  } else if (gid < S_IDX + S_W1) {
    const int l = gid - S_IDX;
    const int o = l & 255, r = l >> 8;          // r in [0,408)
    const int kk = r / CINTOT1, c = r % CINTOT1;
    wT1[l] = (c < 131) ? w1[o * 393 + c * 3 + kk] : 0.f;
  } else if (gid < S_IDX + S_W1 + S_W2) {
    const int l = gid - (S_IDX + S_W1);
    const int o = l & 127, r = l >> 7;          // r in [0,768)
    const int kk = r >> 8, c = r & 255;
    wT2[l] = w2[o * 768 + c * 3 + kk];
  } else if (gid < S_IDX + S_W1 + S_W2 + S_W3) {
    const int l = gid - (S_IDX + S_W1 + S_W2);
    const int o = l & 63, r = l >> 6;           // r in [0,384)
    const int kk = r >> 7, c = r & 127;
    wT3[l] = w3[o * 384 + c * 3 + kk];
  }
}

// ---------------------------------------------------------------------------
// Embedding + collate: one wave per node, ids loaded lane-parallel once.
// ---------------------------------------------------------------------------
__global__ __launch_bounds__(256) void embed_kernel(
    const float* __restrict__ feature,
    const float* __restrict__ col_embed,   // (200,32)
    const float* __restrict__ op_embed,    // (20,32)
    float* __restrict__ collate) {
  const int tid  = threadIdx.x;
  const int wave = tid >> 6;
  const int lane = tid & 63;
  const int b = blockIdx.x >> 5;
  const int n = ((blockIdx.x & 31) << 2) | wave;

  const float* fb = feature + ((size_t)b * 128) * 128 + n;  // stride 128 over d

  int civ = 0, oiv = 0;
  if (lane < MAXP) civ = (int)fb[(OTHER_ + lane) * 128];
  if (lane >= 32 && lane < 32 + MAXP) oiv = (int)fb[(OTHER_ + MAXP + (lane - 32)) * 128];
  const int L = (int)fb[95 * 128];  // wave-uniform

  const float* tp = (lane < 32) ? col_embed : op_embed;
  const int cl = lane & 31;
  float acc = 0.f;
  for (int i = 0; i < L; ++i) {
    const int cv = __shfl(civ, i);
    const int ov = __shfl(oiv, 32 + i);
    const int row = (lane < 32) ? cv : ov;
    acc += tp[row * 32 + cl];
  }

  float* out = collate + ((size_t)b * 128 + n) * CIN1;
  out[35 + lane] = acc;
  if (lane < 35) out[lane] = fb[lane * 128];
  if (lane < 32) out[99 + lane] = fb[(96 + lane) * 128];
}

// ---------------------------------------------------------------------------
// Tree conv v3: block = (batch, chunk), 512 threads, LDS ~38 KB so 3 blocks
// can co-reside per CU. Channels staged in NSTAGE sub-stages of CST (CST%4==0)
// so the staged tile is small; register accs carry across stages.
// wT is kk-major: row r = kk*CINTOT + gc. Output chunk = 64 oc (SPLITJ=false)
// or 64 j (SPLITJ=true). Stats partials per chunk (deterministic combine).
// ---------------------------------------------------------------------------
template <int CINREAL, int CST, int CINP, int CINTOT, int COUTtot, int JPT,
          bool NORM_IN, int NCH_IN, int NSTAGE, int NCHOUT, bool SPLITJ>
__global__ __launch_bounds__(512, 1) void conv_kernel(
    const float* __restrict__ X,        // (B,128,CINREAL) node-major
    const int* __restrict__ idx,        // (B,381)
    const float* __restrict__ wT,       // (3*CINTOT, COUTtot) kk-major
    const float* __restrict__ bias,     // (COUTtot)
    const double* __restrict__ statsIn, // (B, NCH_IN, 2) partials
    float* __restrict__ Y,              // (B,128,COUTtot) node-major
    double* __restrict__ statsOut) {    // (B, NCHOUT, 2) partials
  __shared__ float xs[128 * CINP];
  __shared__ int nb_s[NIDX];
  __shared__ double red[16];

  const int b = blockIdx.x;
  const int chunk = blockIdx.y;
  const int oc0 = SPLITJ ? 0 : chunk * 64;
  const int jbase = SPLITJ ? chunk * 64 : 0;
  const int tid = threadIdx.x;

  float mean = 0.f, inv = 1.f;
  if (NORM_IN) {
    double S = 0.0, Q = 0.0;
#pragma unroll
    for (int i = 0; i < NCH_IN; ++i) {
      S += statsIn[(b * NCH_IN + i) * 2];
      Q += statsIn[(b * NCH_IN + i) * 2 + 1];
    }
    const double cnt = (double)CINREAL * 128.0;
    const double m = S / cnt;
    double var = (Q - S * S / cnt) / (cnt - 1.0);
    if (var < 0.0) var = 0.0;
    mean = (float)m;
    inv = (float)(1.0 / (sqrt(var) + 1e-5));
  }

  const int tx = tid & 15;   // 4 consecutive oc -> 64 oc per chunk
  const int ty = tid >> 4;   // 32 groups of JPT consecutive j

  float acc[4][JPT];
#pragma unroll
  for (int i = 0; i < 4; ++i)
#pragma unroll
    for (int jj = 0; jj < JPT; ++jj) acc[i][jj] = 0.f;

  const float* __restrict__ Xb = X + (size_t)b * (128 * CINREAL);

  int rowoff[JPT][3];
  double s_sum = 0.0, s_sq = 0.0;

  for (int s = 0; s < NSTAGE; ++s) {
    if (s > 0) __syncthreads();  // protect prior-stage reads
    // ---- stage CST channels [s*CST, s*CST+CST) into LDS ----
    for (int t = tid; t < 128 * CST; t += 512) {
      const int n = t / CST;
      const int c = t - n * CST;
      const int gc = s * CST + c;
      float v = 0.f;
      if (gc < CINREAL) {
        v = Xb[n * CINREAL + gc];
        if (NORM_IN) {
          v = (v - mean) * inv;
          v = (v > 0.f) ? v : 0.01f * v;
        }
      }
      xs[n * CINP + c] = v;
    }
    if (s == 0 && tid < NIDX) nb_s[tid] = idx[b * NIDX + tid];
    __syncthreads();

    if (s == 0) {
#pragma unroll
      for (int jj = 0; jj < JPT; ++jj) {
        const int j = jbase + ty * JPT + jj;
#pragma unroll
        for (int kk = 0; kk < 3; ++kk) {
          const int nbv = (j > 0) ? nb_s[(j - 1) * 3 + kk] : 0;
          rowoff[jj][kk] = nbv * CINP;
        }
      }
    }

    const float* wp0 = wT + ((size_t)(0 * CINTOT + s * CST)) * COUTtot + oc0 + tx * 4;
    const float* wp1 = wT + ((size_t)(1 * CINTOT + s * CST)) * COUTtot + oc0 + tx * 4;
    const float* wp2 = wT + ((size_t)(2 * CINTOT + s * CST)) * COUTtot + oc0 + tx * 4;

    for (int c = 0; c < CST; c += 4) {
#pragma unroll
      for (int kk = 0; kk < 3; ++kk) {
        const float* wp = (kk == 0 ? wp0 : kk == 1 ? wp1 : wp2) + c * COUTtot;
        float xq[JPT][4];
#pragma unroll
        for (int jj = 0; jj < JPT; ++jj)
          *reinterpret_cast<float4*>(xq[jj]) =
              *reinterpret_cast<const float4*>(&xs[rowoff[jj][kk] + c]);
#pragma unroll
        for (int cc = 0; cc < 4; ++cc) {
          const float4 w4 = *reinterpret_cast<const float4*>(wp + cc * COUTtot);
#pragma unroll
          for (int jj = 0; jj < JPT; ++jj) {
            const float xv = xq[jj][cc];
            acc[0][jj] = fmaf(w4.x, xv, acc[0][jj]);
            acc[1][jj] = fmaf(w4.y, xv, acc[1][jj]);
            acc[2][jj] = fmaf(w4.z, xv, acc[2][jj]);
            acc[3][jj] = fmaf(w4.w, xv, acc[3][jj]);
          }
        }
      }
    }
  }

  // ---- epilogue: bias, zero column, stats partial, store ----
  const float4 b4 = *reinterpret_cast<const float4*>(bias + oc0 + tx * 4);
#pragma unroll
  for (int jj = 0; jj < JPT; ++jj) {
    const int j = jbase + ty * JPT + jj;
    float4 o4;
    if (j > 0) {
      o4.x = acc[0][jj] + b4.x;
      o4.y = acc[1][jj] + b4.y;
      o4.z = acc[2][jj] + b4.z;
      o4.w = acc[3][jj] + b4.w;
    } else {
      o4.x = 0.f; o4.y = 0.f; o4.z = 0.f; o4.w = 0.f;
    }
    s_sum += (double)o4.x + (double)o4.y + (double)o4.z + (double)o4.w;
    s_sq  += (double)o4.x * o4.x + (double)o4.y * o4.y +
             (double)o4.z * o4.z + (double)o4.w * o4.w;
    *reinterpret_cast<float4*>(Y + ((size_t)b * 128 + j) * COUTtot + oc0 + tx * 4) = o4;
  }

#pragma unroll
  for (int o = 32; o > 0; o >>= 1) {
    s_sum += __shfl_down(s_sum, o, 64);
    s_sq  += __shfl_down(s_sq, o, 64);
  }
  const int w = tid >> 6;
  if ((tid & 63) == 0) { red[w * 2] = s_sum; red[w * 2 + 1] = s_sq; }
  __syncthreads();
  if (tid == 0) {
    double S = 0.0, Q = 0.0;
#pragma unroll
    for (int i = 0; i < 8; ++i) { S += red[i * 2]; Q += red[i * 2 + 1]; }
    statsOut[(b * NCHOUT + chunk) * 2] = S;
    statsOut[(b * NCHOUT + chunk) * 2 + 1] = Q;
  }
}

// ---------------------------------------------------------------------------
// Final: combine conv3 stats partials, normalize, maxpool, 2-layer MLP.
// ---------------------------------------------------------------------------
__global__ __launch_bounds__(64) void final_kernel(
    const float* __restrict__ Y3,      // (B,128,64)
    const double* __restrict__ st,     // (B,2,2) partials
    const float* __restrict__ fw1,     // (32,64)
    const float* __restrict__ fb1,     // (32)
    const float* __restrict__ fw2,     // (1,32)
    const float* __restrict__ fb2,     // (1)
    float* __restrict__ out) {
  const int b = blockIdx.x;
  const int lane = threadIdx.x;

  const double S = st[(b * 2) * 2] + st[(b * 2 + 1) * 2];
  const double Q = st[(b * 2) * 2 + 1] + st[(b * 2 + 1) * 2 + 1];
  const double cnt = 64.0 * 128.0;
  const double m = S / cnt;
  double var = (Q - S * S / cnt) / (cnt - 1.0);
  if (var < 0.0) var = 0.0;
  const float mean = (float)m;
  const float inv = (float)(1.0 / (sqrt(var) + 1e-5));

  const float* Yb = Y3 + (size_t)b * 128 * 64;
  float mx = -3.4e38f;
  for (int n = 0; n < 128; ++n) {
    const float v = (Yb[n * 64 + lane] - mean) * inv;
    mx = fmaxf(mx, v);
  }
  __shared__ float pooled[64];
  __shared__ float hs[32];
  pooled[lane] = mx;
  __syncthreads();
  if (lane < 32) {
    float a = fb1[lane];
    for (int c = 0; c < 64; ++c) a = fmaf(pooled[c], fw1[lane * 64 + c], a);
    hs[lane] = fmaxf(a, 0.f);
  }
  __syncthreads();
  if (lane == 0) {
    float s = fb2[0];
    for (int t = 0; t < 32; ++t) s = fmaf(hs[t], fw2[t], s);
    out[b] = s;
  }
}

// ---------------------------------------------------------------------------
extern "C" void kernel_launch(void* const* d_in, const int* in_sizes, int n_in,
                              void* d_out, int out_size, void* d_ws, size_t ws_size,
                              hipStream_t stream) {
  const float* feature   = (const float*)d_in[0];
  const void*  indexes   = d_in[1];
  const float* col_embed = (const float*)d_in[2];
  const float* op_embed  = (const float*)d_in[3];
  const float* w1  = (const float*)d_in[4];
  const float* b1  = (const float*)d_in[5];
  const float* w2  = (const float*)d_in[6];
  const float* b2  = (const float*)d_in[7];
  const float* w3  = (const float*)d_in[8];
  const float* b3  = (const float*)d_in[9];
  const float* fw1 = (const float*)d_in[10];
  const float* fb1 = (const float*)d_in[11];
  const float* fw2 = (const float*)d_in[12];
  const float* fb2 = (const float*)d_in[13];
  float* out = (float*)d_out;

  char* ws = (char*)d_ws;
  size_t off = 0;
  auto carve = [&](size_t bytes) -> char* {
    off = (off + 255) & ~(size_t)255;
    char* p = ws + off;
    off += bytes;
    return p;
  };
  int*    idx32   = (int*)carve((size_t)S_IDX * sizeof(int));
  float*  wT1     = (float*)carve((size_t)S_W1 * sizeof(float));
  float*  wT2     = (float*)carve((size_t)S_W2 * sizeof(float));
  float*  wT3     = (float*)carve((size_t)S_W3 * sizeof(float));
  float*  collate = (float*)carve((size_t)B_ * 128 * CIN1 * sizeof(float));
  float*  Y1      = (float*)carve((size_t)B_ * 128 * 256 * sizeof(float));
  float*  Y2      = (float*)carve((size_t)B_ * 128 * 128 * sizeof(float));
  float*  Y3      = (float*)carve((size_t)B_ * 128 * 64 * sizeof(float));
  double* st1     = (double*)carve((size_t)B_ * 4 * 2 * sizeof(double));
  double* st2     = (double*)carve((size_t)B_ * 2 * 2 * sizeof(double));
  double* st3     = (double*)carve((size_t)B_ * 2 * 2 * sizeof(double));
  (void)ws_size; (void)in_sizes; (void)n_in; (void)out_size;

  constexpr int PREP_TOTAL = S_IDX + S_W1 + S_W2 + S_W3;
  hipLaunchKernelGGL(prep_kernel, dim3((PREP_TOTAL + 255) / 256), dim3(256), 0, stream,
                     indexes, idx32, w1, wT1, w2, wT2, w3, wT3);
  hipLaunchKernelGGL(embed_kernel, dim3(B_ * 32), dim3(256), 0, stream,
                     feature, col_embed, op_embed, collate);
  // conv1: CIN 131, 2 stages of 68 (CINP 72, LDS 36.9KB), 4 oc-chunks
  hipLaunchKernelGGL((conv_kernel<131, 68, 72, CINTOT1, 256, 4, false, 1, 2, 4, false>),
                     dim3(B_, 4), dim3(512), 0, stream,
                     collate, idx32, wT1, b1, (const double*)nullptr, Y1, st1);
  // conv2: CIN 256, 4 stages of 64 (CINP 68, LDS 34.8KB), 2 oc-chunks
  hipLaunchKernelGGL((conv_kernel<256, 64, 68, CINTOT2, 128, 4, true, 4, 4, 2, false>),
                     dim3(B_, 2), dim3(512), 0, stream,
                     Y1, idx32, wT2, b2, st1, Y2, st2);
  // conv3: CIN 128, 2 stages of 64 (CINP 68), COUT 64, 2 j-halves
  hipLaunchKernelGGL((conv_kernel<128, 64, 68, CINTOT3, 64, 2, true, 2, 2, 2, true>),
                     dim3(B_, 2), dim3(512), 0, stream,
                     Y2, idx32, wT3, b3, st2, Y3, st3);
  hipLaunchKernelGGL(final_kernel, dim3(B_), dim3(64), 0, stream,
                     Y3, st3, fw1, fb1, fw2, fb2, out);
}